// Round 8
// baseline (1109.144 us; speedup 1.0000x reference)
//
#include <hip/hip_runtime.h>
#include <stdint.h>

// ---- problem constants ----
#define GG 10000      // genes
#define H2 512        // 2H
#define KP 10240      // padded K for GEMM1 (32*320, split 8 ways evenly)
#define KCH 1280      // KP/8
#define KSTEPS 40     // KCH/32

// output layout (floats): logits[2048*16] | cell_states[2048*256] | sparsity[1]
//                         | marker_scores[2048*16*10000] | marker_importance[16*10000]
#define O_CS 32768L
#define O_SP 557056L
#define O_MS 557057L
#define O_MI 328237057L

typedef __attribute__((ext_vector_type(8))) short v8s;
typedef __attribute__((ext_vector_type(4))) float v4f;
typedef __attribute__((ext_vector_type(4))) unsigned short u16x4;
typedef __attribute__((ext_vector_type(8))) unsigned short u16x8;

__device__ __forceinline__ unsigned short bf16_rne(float f){
  unsigned u = __float_as_uint(f);
  u += 0x7fffu + ((u>>16)&1u);
  return (unsigned short)(u>>16);
}
__device__ __forceinline__ float bf16_f(unsigned short h){
  return __uint_as_float(((unsigned)h)<<16);
}

// async global->LDS, 16B per lane; lds dest must be wave-uniform base (lane*16 auto)
#define GL16(g,l) __builtin_amdgcn_global_load_lds( \
    (__attribute__((address_space(1))) void*)(uintptr_t)(g), \
    (__attribute__((address_space(3))) void*)(l), 16, 0, 0)

// ---------- split x (2048 x 10000 fp32) -> x_hi bf16 (2048 x 10240, zero pad) ----------
__global__ __launch_bounds__(256) void k_split_x(const float* __restrict__ x,
    unsigned short* __restrict__ xh){
  int idx = blockIdx.x*256 + threadIdx.x;           // 2048*2560 chunks of 4
  int row = idx / (KP/4);
  int k = (idx - row*(KP/4))*4;
  float4 v = make_float4(0.f,0.f,0.f,0.f);
  if (k < GG) v = *(const float4*)(x + (long)row*GG + k);
  float c[4] = {v.x,v.y,v.z,v.w};
  u16x4 hv;
  #pragma unroll
  for (int j=0;j<4;j++) hv[j] = bf16_rne(c[j]);
  *(u16x4*)(xh + (long)row*KP + k) = hv;
}

// ---------- split+transpose enc_w1 (10000 x 512) -> w1t_hi/lo (512 x 10240 bf16) ----------
__global__ __launch_bounds__(256) void k_split_w1t(const float* __restrict__ w1,
    unsigned short* __restrict__ wth, unsigned short* __restrict__ wtl){
  __shared__ unsigned T[64][65];
  int k0 = blockIdx.x*64, n0 = blockIdx.y*64;
  int tid = threadIdx.x;
  {
    int kr = tid>>2, nc = (tid&3)*16;
    int kk = k0 + kr;
    #pragma unroll
    for (int j=0;j<16;j+=4){
      float4 v = make_float4(0.f,0.f,0.f,0.f);
      if (kk < GG) v = *(const float4*)(w1 + (long)kk*H2 + n0 + nc + j);
      float c[4] = {v.x,v.y,v.z,v.w};
      #pragma unroll
      for (int jj=0;jj<4;jj++){
        unsigned short h = bf16_rne(c[jj]);
        unsigned short l = bf16_rne(c[jj] - bf16_f(h));
        T[kr][nc+j+jj] = (unsigned)h | ((unsigned)l<<16);
      }
    }
  }
  __syncthreads();
  {
    int n = tid>>2, kc = (tid&3)*16;
    u16x8 h0, h1, l0, l1;
    #pragma unroll
    for (int j=0;j<8;j++){
      unsigned a = T[kc+j][n];
      unsigned b = T[kc+8+j][n];
      h0[j] = (unsigned short)(a & 0xffffu); l0[j] = (unsigned short)(a>>16);
      h1[j] = (unsigned short)(b & 0xffffu); l1[j] = (unsigned short)(b>>16);
    }
    long off = (long)(n0+n)*KP + k0 + kc;
    *(u16x8*)(wth+off)   = h0; *(u16x8*)(wth+off+8) = h1;
    *(u16x8*)(wtl+off)   = l0; *(u16x8*)(wtl+off+8) = l1;
  }
}

// ---------- GEMM1: (2048x10240) @ (10240x512) 2-term split-bf16 MFMA, split-K=8 ----------
__global__ __launch_bounds__(256) void k_gemm1(
    const unsigned short* __restrict__ xh,
    const unsigned short* __restrict__ wth, const unsigned short* __restrict__ wtl,
    float* __restrict__ pc){
  __shared__ unsigned short Ah[4096], Bh[4096], Bl[4096]; // [128 rows][32 k] bf16 each
  const int tid = threadIdx.x;
  const int wid = tid>>6, lane = tid&63;
  const int bm = blockIdx.x, bn = blockIdx.y, kz = blockIdx.z;
  const int c0 = wid*2, c1 = c0+1;
  const int srow = lane>>2;
  const int sk8 = (lane&3)*8;
  const long kb0 = (long)kz*KCH + sk8;
  const long rA0 = (long)(bm*128 + c0*16 + srow)*KP + kb0;
  const long rA1 = (long)(bm*128 + c1*16 + srow)*KP + kb0;
  const long rB0 = (long)(bn*128 + c0*16 + srow)*KP + kb0;
  const long rB1 = (long)(bn*128 + c1*16 + srow)*KP + kb0;
  const unsigned short* pAh0 = xh + rA0;  const unsigned short* pAh1 = xh + rA1;
  const unsigned short* pBh0 = wth + rB0; const unsigned short* pBh1 = wth + rB1;
  const unsigned short* pBl0 = wtl + rB0; const unsigned short* pBl1 = wtl + rB1;
  unsigned short* dAh0 = &Ah[c0*512]; unsigned short* dAh1 = &Ah[c1*512];
  unsigned short* dBh0 = &Bh[c0*512]; unsigned short* dBh1 = &Bh[c1*512];
  unsigned short* dBl0 = &Bl[c0*512]; unsigned short* dBl1 = &Bl[c1*512];
  const int wr = wid>>1, wc = wid&1;      // wave -> 64x64 quadrant
  const int fr = lane&15, fq = lane>>4;
  v4f acc[4][4];
  #pragma unroll
  for (int m=0;m<4;m++)
    #pragma unroll
    for (int n=0;n<4;n++){ v4f z = {0.f,0.f,0.f,0.f}; acc[m][n] = z; }

  for (int s=0; s<KSTEPS; ++s){
    GL16(pAh0, dAh0); GL16(pAh1, dAh1);
    GL16(pBh0, dBh0); GL16(pBh1, dBh1);
    GL16(pBl0, dBl0); GL16(pBl1, dBl1);
    pAh0 += 32; pAh1 += 32;
    pBh0 += 32; pBh1 += 32; pBl0 += 32; pBl1 += 32;
    __syncthreads();
    v8s ah[4], bh[4], bl[4];
    #pragma unroll
    for (int m=0;m<4;m++)
      ah[m] = *(const v8s*)&Ah[(wr*64 + m*16 + fr)*32 + fq*8];
    #pragma unroll
    for (int n=0;n<4;n++){
      int off = (wc*64 + n*16 + fr)*32 + fq*8;
      bh[n] = *(const v8s*)&Bh[off];
      bl[n] = *(const v8s*)&Bl[off];
    }
    #pragma unroll
    for (int m=0;m<4;m++)
      #pragma unroll
      for (int n=0;n<4;n++){
        acc[m][n] = __builtin_amdgcn_mfma_f32_16x16x32_bf16(ah[m], bh[n], acc[m][n], 0,0,0);
        acc[m][n] = __builtin_amdgcn_mfma_f32_16x16x32_bf16(ah[m], bl[n], acc[m][n], 0,0,0);
      }
    __syncthreads();
  }
  float* op = pc + (long)kz*(2048L*512L);
  #pragma unroll
  for (int m=0;m<4;m++){
    #pragma unroll
    for (int n=0;n<4;n++){
      int col = bn*128 + wc*64 + n*16 + fr;
      #pragma unroll
      for (int r=0;r<4;r++){
        int row = bm*128 + wr*64 + m*16 + fq*4 + r;
        op[(long)row*512 + col] = acc[m][n][r];
      }
    }
  }
}

// ---------- reduce split-K partials + bias + LayerNorm + ReLU -> t1 (2048x512) ----------
__global__ __launch_bounds__(256) void k_reduce_ln(const float* __restrict__ pc,
    const float* __restrict__ b1, const float* __restrict__ g, const float* __restrict__ b,
    float* __restrict__ t1){
  __shared__ float red[8];
  int row = blockIdx.x, tid = threadIdx.x;
  long base = (long)row*512;
  float v0 = b1[tid], v1 = b1[tid+256];
  #pragma unroll
  for (int kz=0;kz<8;kz++){
    v0 += pc[(long)kz*1048576 + base + tid];
    v1 += pc[(long)kz*1048576 + base + tid + 256];
  }
  float s = v0+v1, q = v0*v0 + v1*v1;
  #pragma unroll
  for (int off=32; off; off>>=1){ s += __shfl_xor(s, off); q += __shfl_xor(q, off); }
  if ((tid&63)==0){ red[tid>>6] = s; red[4+(tid>>6)] = q; }
  __syncthreads();
  float sum = red[0]+red[1]+red[2]+red[3];
  float ssq = red[4]+red[5]+red[6]+red[7];
  float mean = sum*(1.f/512.f);
  float var  = ssq*(1.f/512.f) - mean*mean;
  float rstd = rsqrtf(var + 1e-5f);
  float r0 = (v0-mean)*rstd*g[tid]     + b[tid];
  float r1 = (v1-mean)*rstd*g[tid+256] + b[tid+256];
  t1[base+tid]     = fmaxf(r0, 0.f);
  t1[base+tid+256] = fmaxf(r1, 0.f);
}

// ---------- generic small fp32 GEMM: C(2048xN=256ish) = A @ W + bias, 64x64 tile ----------
__global__ __launch_bounds__(256) void k_gemm_f32(
    const float* __restrict__ A, int lda,
    const float* __restrict__ W, int ldw,
    const float* __restrict__ bias,
    float* __restrict__ C, int ldo, int K){
  __shared__ float As[64][36];
  __shared__ float WsT[64][36];   // [col][k]
  const int tid = threadIdx.x;
  const int bx = blockIdx.x, by = blockIdx.y;
  const int tx = tid&15, ty = tid>>4;
  const int ar = tid>>2, ak = (tid&3)*8;
  const int wr2 = tid>>3, wc2 = (tid&7)*8;
  float acc[4][4];
  #pragma unroll
  for (int i=0;i<4;i++)
    #pragma unroll
    for (int j=0;j<4;j++) acc[i][j] = 0.f;
  for (int kb=0; kb<K; kb+=32){
    float4 a0 = *(const float4*)(A + (long)(bx*64+ar)*lda + kb + ak);
    float4 a1 = *(const float4*)(A + (long)(bx*64+ar)*lda + kb + ak + 4);
    float4 w0 = *(const float4*)(W + (long)(kb+wr2)*ldw + by*64 + wc2);
    float4 w1v= *(const float4*)(W + (long)(kb+wr2)*ldw + by*64 + wc2 + 4);
    __syncthreads();
    *(float4*)&As[ar][ak]   = a0;
    *(float4*)&As[ar][ak+4] = a1;
    float cw[8] = {w0.x,w0.y,w0.z,w0.w,w1v.x,w1v.y,w1v.z,w1v.w};
    #pragma unroll
    for (int jj=0;jj<8;jj++) WsT[wc2+jj][wr2] = cw[jj];
    __syncthreads();
    #pragma unroll
    for (int k4=0;k4<8;k4++){
      float4 av[4], wv[4];
      #pragma unroll
      for (int i=0;i<4;i++) av[i] = *(const float4*)&As[ty + i*16][k4*4];
      #pragma unroll
      for (int j=0;j<4;j++) wv[j] = *(const float4*)&WsT[tx + j*16][k4*4];
      #pragma unroll
      for (int i=0;i<4;i++)
        #pragma unroll
        for (int j=0;j<4;j++)
          acc[i][j] += av[i].x*wv[j].x + av[i].y*wv[j].y + av[i].z*wv[j].z + av[i].w*wv[j].w;
    }
  }
  #pragma unroll
  for (int i=0;i<4;i++){
    int r = bx*64 + ty + i*16;
    #pragma unroll
    for (int j=0;j<4;j++){
      int c = by*64 + tx + j*16;
      C[(long)r*ldo + c] = acc[i][j] + bias[c];
    }
  }
}

// ---------- residual add + LayerNorm over 256 ----------
__global__ __launch_bounds__(256) void k_add_ln(const float* __restrict__ o,
    const float* __restrict__ res, const float* __restrict__ g, const float* __restrict__ b,
    float* __restrict__ fout){
  __shared__ float red[8];
  int row = blockIdx.x, tid = threadIdx.x;
  long base = (long)row*256;
  float x = o[base+tid] + res[base+tid];
  float s = x, q = x*x;
  #pragma unroll
  for (int off=32; off; off>>=1){ s += __shfl_xor(s, off); q += __shfl_xor(q, off); }
  if ((tid&63)==0){ red[tid>>6] = s; red[4+(tid>>6)] = q; }
  __syncthreads();
  float sum = red[0]+red[1]+red[2]+red[3];
  float ssq = red[4]+red[5]+red[6]+red[7];
  float mean = sum*(1.f/256.f);
  float var  = ssq*(1.f/256.f) - mean*mean;
  float rstd = rsqrtf(var + 1e-5f);
  fout[base+tid] = (x-mean)*rstd*g[tid] + b[tid];
}

// ---------- head: cosine sim -> softmax/0.5 -> cell_states -> MLP logits ----------
__global__ __launch_bounds__(256) void k_head(const float* __restrict__ f,
    const float* __restrict__ protos, const float* __restrict__ w1, const float* __restrict__ b1,
    const float* __restrict__ w2, const float* __restrict__ b2,
    float* __restrict__ logits, float* __restrict__ cs_out){
  __shared__ float ff[256], csb[256], hid[128], simr[32], pnl[32], sw[32], red[8];
  int row = blockIdx.x, tid = threadIdx.x;
  float fv = f[(long)row*256 + tid];
  ff[tid] = fv;
  float s = fv*fv;
  #pragma unroll
  for (int off=32; off; off>>=1) s += __shfl_xor(s, off);
  if ((tid&63)==0) red[tid>>6] = s;
  __syncthreads();
  float fn = sqrtf(red[0]+red[1]+red[2]+red[3]);
  int p = tid>>3, e = tid&7;
  float d = 0.f, q = 0.f;
  for (int k=e*32; k<e*32+32; k++){ float pv = protos[p*256+k]; d += ff[k]*pv; q += pv*pv; }
  d += __shfl_xor(d,1); q += __shfl_xor(q,1);
  d += __shfl_xor(d,2); q += __shfl_xor(q,2);
  d += __shfl_xor(d,4); q += __shfl_xor(q,4);
  if (e==0){ simr[p] = d; pnl[p] = sqrtf(q); }
  __syncthreads();
  if (tid < 64){
    float z = (tid<32) ? (2.f*simr[tid]/fmaxf(fn*pnl[tid], 1e-8f)) : -3e38f;
    float m = z;
    #pragma unroll
    for (int off=16; off; off>>=1) m = fmaxf(m, __shfl_xor(m, off));
    float ev = (tid<32) ? expf(z - m) : 0.f;
    float sm = ev;
    #pragma unroll
    for (int off=16; off; off>>=1) sm += __shfl_xor(sm, off);
    if (tid<32) sw[tid] = ev/sm;
  }
  __syncthreads();
  float cs = 0.f;
  #pragma unroll 8
  for (int pp=0;pp<32;pp++) cs += sw[pp]*protos[pp*256+tid];
  cs_out[(long)row*256+tid] = cs;
  csb[tid] = cs;
  __syncthreads();
  if (tid<128){
    float hv = b1[tid];
    for (int k=0;k<256;k++) hv += csb[k]*w1[k*128+tid];
    hid[tid] = fmaxf(hv, 0.f);
  }
  __syncthreads();
  if (tid<16){
    float lv = b2[tid];
    for (int j=0;j<128;j++) lv += hid[j]*w2[j*16+tid];
    logits[(long)row*16+tid] = lv;
  }
}

// ---------- sparsity scalar ----------
__global__ void k_misc(float* __restrict__ out){
  if (threadIdx.x==0 && blockIdx.x==0) out[O_SP] = 0.01f/10000.0f;
}

// ---------- marker_scores broadcast fill ----------
__global__ __launch_bounds__(256) void k_fill_marker(const float* __restrict__ mw,
    float* __restrict__ out){
  int b = blockIdx.y;
  int t = blockIdx.x*256 + threadIdx.x;
  float* base = out + O_MS + (long)b*160000;
  if (t < 40000){
    int i = 4*t;
    float4 A  = *(const float4*)(mw + i);
    float4 Bv = (i+4 < 160000) ? *(const float4*)(mw + i + 4) : *(const float4*)(mw);
    float4 v = make_float4(A.w, Bv.x, Bv.y, Bv.z);
    *(float4*)(base + 3 + i) = v;
  }
  if (b==0 && t<3) base[t] = mw[t];
}

// ---------- marker_importance: per-class L1 normalize ----------
__global__ __launch_bounds__(256) void k_importance(const float* __restrict__ mw,
    float* __restrict__ out){
  __shared__ float red[4];
  int c = blockIdx.x, tid = threadIdx.x;
  float s = 0.f;
  for (int g0=tid; g0<10000; g0+=256) s += fabsf(mw[c*10000+g0]);
  #pragma unroll
  for (int off=32; off; off>>=1) s += __shfl_xor(s, off);
  if ((tid&63)==0) red[tid>>6] = s;
  __syncthreads();
  float inv = 1.f/fmaxf(red[0]+red[1]+red[2]+red[3], 1e-12f);
  for (int g0=tid; g0<10000; g0+=256)
    out[O_MI + (long)c*10000 + g0] = mw[c*10000+g0]*inv;
}

extern "C" void kernel_launch(void* const* d_in, const int* in_sizes, int n_in,
                              void* d_out, int out_size, void* d_ws, size_t ws_size,
                              hipStream_t stream){
  const float* x        = (const float*)d_in[0];
  const float* enc_w1   = (const float*)d_in[1];
  const float* enc_b1   = (const float*)d_in[2];
  const float* enc_ln_g = (const float*)d_in[3];
  const float* enc_ln_b = (const float*)d_in[4];
  const float* enc_w2   = (const float*)d_in[5];
  const float* enc_b2   = (const float*)d_in[6];
  const float* qkv_w    = (const float*)d_in[9];
  const float* qkv_b    = (const float*)d_in[10];
  const float* out_w    = (const float*)d_in[11];
  const float* out_b    = (const float*)d_in[12];
  const float* ln_g     = (const float*)d_in[13];
  const float* ln_b     = (const float*)d_in[14];
  const float* protos   = (const float*)d_in[15];
  const float* clf_w1   = (const float*)d_in[16];
  const float* clf_b1   = (const float*)d_in[17];
  const float* clf_w2   = (const float*)d_in[18];
  const float* clf_b2   = (const float*)d_in[19];
  const float* mw       = (const float*)d_in[20];
  float* out = (float*)d_out;

  char* scr = (char*)(((uintptr_t)d_out + O_MS*4 + 255) & ~(uintptr_t)255);
  unsigned short* xh  = (unsigned short*)(scr);
  unsigned short* wth = (unsigned short*)(scr + 83886080L);
  unsigned short* wtl = (unsigned short*)(scr + 94371840L);
  float* pc = (float*)(scr + 104857600L);
  float* t1 = (float*)(scr + 138412032L);
  float* f0 = (float*)(scr + 142606336L);
  float* f1 = (float*)(scr + 144703488L);
  float* vb = (float*)(scr + 146800640L);
  float* ob = (float*)(scr + 148897792L);

  k_split_x  <<<20480, 256, 0, stream>>>(x, xh);
  k_split_w1t<<<dim3(160, 8), 256, 0, stream>>>(enc_w1, wth, wtl);
  k_gemm1    <<<dim3(16, 4, 8), 256, 0, stream>>>(xh, wth, wtl, pc);

  // ===== MEASUREMENT: run the middle section 4x (idempotent; Δdur = 3 x middle cost) =====
  for (int rep = 0; rep < 4; ++rep){
    k_reduce_ln<<<2048, 256, 0, stream>>>(pc, enc_b1, enc_ln_g, enc_ln_b, t1);
    k_gemm_f32 <<<dim3(32, 4), 256, 0, stream>>>(t1, 512, enc_w2, 256, enc_b2, f0, 256, 512);
    const float* fin = f0; float* fo = f1;
    for (int i=0;i<3;i++){
      k_gemm_f32<<<dim3(32,4), 256, 0, stream>>>(fin, 256, qkv_w + (long)i*196608 + 512, 768,
                                                 qkv_b + i*768 + 512, vb, 256, 256);
      k_gemm_f32<<<dim3(32,4), 256, 0, stream>>>(vb, 256, out_w + (long)i*65536, 256,
                                                 out_b + i*256, ob, 256, 256);
      k_add_ln  <<<2048, 256, 0, stream>>>(ob, fin, ln_g + i*256, ln_b + i*256, fo);
      const float* tmp = fo; fo = (float*)fin; fin = tmp;
    }
    k_head<<<2048, 256, 0, stream>>>(fin, protos, clf_w1, clf_b1, clf_w2, clf_b2,
                                     out, out + O_CS);
    k_misc<<<1, 64, 0, stream>>>(out);
  }

  k_fill_marker<<<dim3(157, 2048), 256, 0, stream>>>(mw, out);
  k_importance <<<16, 256, 0, stream>>>(mw, out);
}

// Round 9
// 593.847 us; speedup vs baseline: 1.8677x; 1.8677x over previous
//
#include <hip/hip_runtime.h>
#include <stdint.h>

// ---- problem constants ----
#define GG 10000      // genes
#define H2 512        // 2H
#define KP 10240      // padded K for GEMM1 (32*320, split 8 ways evenly)
#define KCH 1280      // KP/8
#define KSTEPS 40     // KCH/32

// output layout (floats): logits[2048*16] | cell_states[2048*256] | sparsity[1]
//                         | marker_scores[2048*16*10000] | marker_importance[16*10000]
#define O_CS 32768L
#define O_SP 557056L
#define O_MS 557057L
#define O_MI 328237057L

typedef __attribute__((ext_vector_type(8))) short v8s;
typedef __attribute__((ext_vector_type(4))) float v4f;
typedef __attribute__((ext_vector_type(4))) unsigned short u16x4;
typedef __attribute__((ext_vector_type(8))) unsigned short u16x8;

__device__ __forceinline__ unsigned short bf16_rne(float f){
  unsigned u = __float_as_uint(f);
  u += 0x7fffu + ((u>>16)&1u);
  return (unsigned short)(u>>16);
}
__device__ __forceinline__ float bf16_f(unsigned short h){
  return __uint_as_float(((unsigned)h)<<16);
}

#define GL16(g,l) __builtin_amdgcn_global_load_lds( \
    (__attribute__((address_space(1))) void*)(uintptr_t)(g), \
    (__attribute__((address_space(3))) void*)(l), 16, 0, 0)

// ---------- prep0: Wc[i] = qkv_w[i][:,512:768] @ out_w[i]; bc[i] = qkv_b_v @ out_w + out_b ----
// (proven correct in R7, absmax 0.0039)
__global__ __launch_bounds__(256) void k_prep0(const float* __restrict__ qkv_w,
    const float* __restrict__ qkv_b, const float* __restrict__ out_w,
    const float* __restrict__ out_b, float* __restrict__ Wc, float* __restrict__ bc){
  __shared__ float As[64][36];
  __shared__ float WsT[64][36];
  const int bid = blockIdx.x, tid = threadIdx.x;
  if (bid < 48){
    const int z = bid>>4, bx = (bid&15)>>2, by = bid&3;
    const float* A = qkv_w + (long)z*196608 + 512;   // lda=768, V-slice
    const float* W = out_w + (long)z*65536;          // ldw=256
    float* C = Wc + (long)z*65536;
    const int tx = tid&15, ty = tid>>4;
    const int ar = tid>>2, ak = (tid&3)*8;
    const int wr2 = tid>>3, wc2 = (tid&7)*8;
    float acc[4][4];
    #pragma unroll
    for (int i=0;i<4;i++)
      #pragma unroll
      for (int j=0;j<4;j++) acc[i][j] = 0.f;
    for (int kb=0; kb<256; kb+=32){
      float4 a0 = *(const float4*)(A + (long)(bx*64+ar)*768 + kb + ak);
      float4 a1 = *(const float4*)(A + (long)(bx*64+ar)*768 + kb + ak + 4);
      float4 w0 = *(const float4*)(W + (long)(kb+wr2)*256 + by*64 + wc2);
      float4 w1v= *(const float4*)(W + (long)(kb+wr2)*256 + by*64 + wc2 + 4);
      __syncthreads();
      *(float4*)&As[ar][ak]   = a0;
      *(float4*)&As[ar][ak+4] = a1;
      float cw[8] = {w0.x,w0.y,w0.z,w0.w,w1v.x,w1v.y,w1v.z,w1v.w};
      #pragma unroll
      for (int jj=0;jj<8;jj++) WsT[wc2+jj][wr2] = cw[jj];
      __syncthreads();
      #pragma unroll
      for (int k4=0;k4<8;k4++){
        float4 av[4], wv[4];
        #pragma unroll
        for (int i=0;i<4;i++) av[i] = *(const float4*)&As[ty + i*16][k4*4];
        #pragma unroll
        for (int j=0;j<4;j++) wv[j] = *(const float4*)&WsT[tx + j*16][k4*4];
        #pragma unroll
        for (int i=0;i<4;i++)
          #pragma unroll
          for (int j=0;j<4;j++)
            acc[i][j] += av[i].x*wv[j].x + av[i].y*wv[j].y + av[i].z*wv[j].z + av[i].w*wv[j].w;
      }
    }
    #pragma unroll
    for (int i=0;i<4;i++){
      int r = bx*64 + ty + i*16;
      #pragma unroll
      for (int j=0;j<4;j++)
        C[(long)r*256 + by*64 + tx + j*16] = acc[i][j];
    }
  } else {
    int i = bid - 48;                      // 0..2
    float acc = out_b[i*256 + tid];
    const float* wo = out_w + (long)i*65536;
    const float* qb = qkv_b + i*768 + 512;
    for (int j=0;j<256;j++) acc += qb[j]*wo[j*256+tid];
    bc[i*256+tid] = acc;
  }
}

// ---------- split x (2048 x 10000 fp32) -> x_hi bf16 (2048 x 10240, zero pad) ----------
__global__ __launch_bounds__(256) void k_split_x(const float* __restrict__ x,
    unsigned short* __restrict__ xh){
  int idx = blockIdx.x*256 + threadIdx.x;
  int row = idx / (KP/4);
  int k = (idx - row*(KP/4))*4;
  float4 v = make_float4(0.f,0.f,0.f,0.f);
  if (k < GG) v = *(const float4*)(x + (long)row*GG + k);
  float c[4] = {v.x,v.y,v.z,v.w};
  u16x4 hv;
  #pragma unroll
  for (int j=0;j<4;j++) hv[j] = bf16_rne(c[j]);
  *(u16x4*)(xh + (long)row*KP + k) = hv;
}

// ---------- split+transpose enc_w1 (10000 x 512) -> w1t_hi/lo (512 x 10240 bf16) ----------
__global__ __launch_bounds__(256) void k_split_w1t(const float* __restrict__ w1,
    unsigned short* __restrict__ wth, unsigned short* __restrict__ wtl){
  __shared__ unsigned T[64][65];
  int k0 = blockIdx.x*64, n0 = blockIdx.y*64;
  int tid = threadIdx.x;
  {
    int kr = tid>>2, nc = (tid&3)*16;
    int kk = k0 + kr;
    #pragma unroll
    for (int j=0;j<16;j+=4){
      float4 v = make_float4(0.f,0.f,0.f,0.f);
      if (kk < GG) v = *(const float4*)(w1 + (long)kk*H2 + n0 + nc + j);
      float c[4] = {v.x,v.y,v.z,v.w};
      #pragma unroll
      for (int jj=0;jj<4;jj++){
        unsigned short h = bf16_rne(c[jj]);
        unsigned short l = bf16_rne(c[jj] - bf16_f(h));
        T[kr][nc+j+jj] = (unsigned)h | ((unsigned)l<<16);
      }
    }
  }
  __syncthreads();
  {
    int n = tid>>2, kc = (tid&3)*16;
    u16x8 h0, h1, l0, l1;
    #pragma unroll
    for (int j=0;j<8;j++){
      unsigned a = T[kc+j][n];
      unsigned b = T[kc+8+j][n];
      h0[j] = (unsigned short)(a & 0xffffu); l0[j] = (unsigned short)(a>>16);
      h1[j] = (unsigned short)(b & 0xffffu); l1[j] = (unsigned short)(b>>16);
    }
    long off = (long)(n0+n)*KP + k0 + kc;
    *(u16x8*)(wth+off)   = h0; *(u16x8*)(wth+off+8) = h1;
    *(u16x8*)(wtl+off)   = l0; *(u16x8*)(wtl+off+8) = l1;
  }
}

// ---------- GEMM1: (2048x10240) @ (10240x512) 2-term split-bf16 MFMA, split-K=8 ----------
// (R5 measured-best version, unchanged)
__global__ __launch_bounds__(256) void k_gemm1(
    const unsigned short* __restrict__ xh,
    const unsigned short* __restrict__ wth, const unsigned short* __restrict__ wtl,
    float* __restrict__ pc){
  __shared__ unsigned short Ah[4096], Bh[4096], Bl[4096];
  const int tid = threadIdx.x;
  const int wid = tid>>6, lane = tid&63;
  const int bm = blockIdx.x, bn = blockIdx.y, kz = blockIdx.z;
  const int c0 = wid*2, c1 = c0+1;
  const int srow = lane>>2;
  const int sk8 = (lane&3)*8;
  const long kb0 = (long)kz*KCH + sk8;
  const long rA0 = (long)(bm*128 + c0*16 + srow)*KP + kb0;
  const long rA1 = (long)(bm*128 + c1*16 + srow)*KP + kb0;
  const long rB0 = (long)(bn*128 + c0*16 + srow)*KP + kb0;
  const long rB1 = (long)(bn*128 + c1*16 + srow)*KP + kb0;
  const unsigned short* pAh0 = xh + rA0;  const unsigned short* pAh1 = xh + rA1;
  const unsigned short* pBh0 = wth + rB0; const unsigned short* pBh1 = wth + rB1;
  const unsigned short* pBl0 = wtl + rB0; const unsigned short* pBl1 = wtl + rB1;
  unsigned short* dAh0 = &Ah[c0*512]; unsigned short* dAh1 = &Ah[c1*512];
  unsigned short* dBh0 = &Bh[c0*512]; unsigned short* dBh1 = &Bh[c1*512];
  unsigned short* dBl0 = &Bl[c0*512]; unsigned short* dBl1 = &Bl[c1*512];
  const int wr = wid>>1, wc = wid&1;
  const int fr = lane&15, fq = lane>>4;
  v4f acc[4][4];
  #pragma unroll
  for (int m=0;m<4;m++)
    #pragma unroll
    for (int n=0;n<4;n++){ v4f z = {0.f,0.f,0.f,0.f}; acc[m][n] = z; }

  for (int s=0; s<KSTEPS; ++s){
    GL16(pAh0, dAh0); GL16(pAh1, dAh1);
    GL16(pBh0, dBh0); GL16(pBh1, dBh1);
    GL16(pBl0, dBl0); GL16(pBl1, dBl1);
    pAh0 += 32; pAh1 += 32;
    pBh0 += 32; pBh1 += 32; pBl0 += 32; pBl1 += 32;
    __syncthreads();
    v8s ah[4], bh[4], bl[4];
    #pragma unroll
    for (int m=0;m<4;m++)
      ah[m] = *(const v8s*)&Ah[(wr*64 + m*16 + fr)*32 + fq*8];
    #pragma unroll
    for (int n=0;n<4;n++){
      int off = (wc*64 + n*16 + fr)*32 + fq*8;
      bh[n] = *(const v8s*)&Bh[off];
      bl[n] = *(const v8s*)&Bl[off];
    }
    #pragma unroll
    for (int m=0;m<4;m++)
      #pragma unroll
      for (int n=0;n<4;n++){
        acc[m][n] = __builtin_amdgcn_mfma_f32_16x16x32_bf16(ah[m], bh[n], acc[m][n], 0,0,0);
        acc[m][n] = __builtin_amdgcn_mfma_f32_16x16x32_bf16(ah[m], bl[n], acc[m][n], 0,0,0);
      }
    __syncthreads();
  }
  float* op = pc + (long)kz*(2048L*512L);
  #pragma unroll
  for (int m=0;m<4;m++){
    #pragma unroll
    for (int n=0;n<4;n++){
      int col = bn*128 + wc*64 + n*16 + fr;
      #pragma unroll
      for (int r=0;r<4;r++){
        int row = bm*128 + wr*64 + m*16 + fq*4 + r;
        op[(long)row*512 + col] = acc[m][n][r];
      }
    }
  }
}

// ---------- reduce split-K partials + bias + LayerNorm + ReLU -> t1 (2048x512) ----------
__global__ __launch_bounds__(256) void k_reduce_ln(const float* __restrict__ pc,
    const float* __restrict__ b1, const float* __restrict__ g, const float* __restrict__ b,
    float* __restrict__ t1){
  __shared__ float red[8];
  int row = blockIdx.x, tid = threadIdx.x;
  long base = (long)row*512;
  float v0 = b1[tid], v1 = b1[tid+256];
  #pragma unroll
  for (int kz=0;kz<8;kz++){
    v0 += pc[(long)kz*1048576 + base + tid];
    v1 += pc[(long)kz*1048576 + base + tid + 256];
  }
  float s = v0+v1, q = v0*v0 + v1*v1;
  #pragma unroll
  for (int off=32; off; off>>=1){ s += __shfl_xor(s, off); q += __shfl_xor(q, off); }
  if ((tid&63)==0){ red[tid>>6] = s; red[4+(tid>>6)] = q; }
  __syncthreads();
  float sum = red[0]+red[1]+red[2]+red[3];
  float ssq = red[4]+red[5]+red[6]+red[7];
  float mean = sum*(1.f/512.f);
  float var  = ssq*(1.f/512.f) - mean*mean;
  float rstd = rsqrtf(var + 1e-5f);
  float r0 = (v0-mean)*rstd*g[tid]     + b[tid];
  float r1 = (v1-mean)*rstd*g[tid+256] + b[tid+256];
  t1[base+tid]     = fmaxf(r0, 0.f);
  t1[base+tid+256] = fmaxf(r1, 0.f);
}

// ---------- fused row-GEMM: out(2048x256) = A(2048xK)@W + bias [+residual+LN] ----------
// 512 blocks x 4 rows; W streamed via LDS in 32-row chunks; 40KB LDS -> 4 blocks/CU.
__global__ __launch_bounds__(256) void k_rowgemm(
    const float* __restrict__ A, const float* __restrict__ W,
    const float* __restrict__ bias, const float* __restrict__ g, const float* __restrict__ b,
    float* __restrict__ out, int K, int doLN){
  __shared__ float As[4][512];
  __shared__ float Ws[32][256];
  __shared__ float rs[4][4], rq[4][4];
  const int tid = threadIdx.x;
  const long r0 = (long)blockIdx.x * 4;
  const int kq = K>>2;                    // float4s per row
  for (int p = tid; p < K; p += 256){     // 4 rows * K/4 = K float4 loads
    int row = p / kq;
    int c4 = (p - row*kq)*4;
    *(float4*)&As[row][c4] = *(const float4*)(A + (r0+row)*K + c4);
  }
  float acc[4] = {0.f,0.f,0.f,0.f};
  const int nc = K>>5;
  __syncthreads();
  for (int c = 0; c < nc; ++c){
    const float* Wb = W + (long)(c*32)*256;
    #pragma unroll
    for (int u=0; u<8; u++){
      int p2 = u*256 + tid;
      int j = p2 >> 6, c4 = (p2 & 63)*4;
      *(float4*)&Ws[j][c4] = *(const float4*)(Wb + j*256 + c4);
    }
    __syncthreads();
    #pragma unroll
    for (int j=0;j<32;j+=4){
      float w0 = Ws[j][tid], w1 = Ws[j+1][tid], w2 = Ws[j+2][tid], w3 = Ws[j+3][tid];
      #pragma unroll
      for (int r=0;r<4;r++){
        float4 a = *(const float4*)&As[r][c*32+j];
        acc[r] += a.x*w0 + a.y*w1 + a.z*w2 + a.w*w3;
      }
    }
    __syncthreads();
  }
  float bv = bias[tid];
  if (doLN){
    const int w = tid>>6, lane = tid&63;
    float xv[4];
    #pragma unroll
    for (int r=0;r<4;r++) xv[r] = acc[r] + bv + As[r][tid];   // +residual (K==256)
    #pragma unroll
    for (int r=0;r<4;r++){
      float s = xv[r], q = xv[r]*xv[r];
      #pragma unroll
      for (int off=32; off; off>>=1){ s += __shfl_xor(s,off); q += __shfl_xor(q,off); }
      if (lane==0){ rs[r][w] = s; rq[r][w] = q; }
    }
    __syncthreads();
    float gv = g[tid], bbv = b[tid];
    #pragma unroll
    for (int r=0;r<4;r++){
      float sum = rs[r][0]+rs[r][1]+rs[r][2]+rs[r][3];
      float ssq = rq[r][0]+rq[r][1]+rq[r][2]+rq[r][3];
      float mean = sum*(1.f/256.f);
      float var  = ssq*(1.f/256.f) - mean*mean;
      float rstd = rsqrtf(var + 1e-5f);
      out[(r0+r)*256 + tid] = (xv[r]-mean)*rstd*gv + bbv;
    }
  } else {
    #pragma unroll
    for (int r=0;r<4;r++) out[(r0+r)*256 + tid] = acc[r] + bv;
  }
}

// ---------- head: cosine sim -> softmax/0.5 -> cell_states -> MLP logits ----------
__global__ __launch_bounds__(256) void k_head(const float* __restrict__ f,
    const float* __restrict__ protos, const float* __restrict__ w1, const float* __restrict__ b1,
    const float* __restrict__ w2, const float* __restrict__ b2,
    float* __restrict__ logits, float* __restrict__ cs_out){
  __shared__ float ff[256], csb[256], hid[128], simr[32], pnl[32], sw[32], red[8];
  int row = blockIdx.x, tid = threadIdx.x;
  float fv = f[(long)row*256 + tid];
  ff[tid] = fv;
  float s = fv*fv;
  #pragma unroll
  for (int off=32; off; off>>=1) s += __shfl_xor(s, off);
  if ((tid&63)==0) red[tid>>6] = s;
  __syncthreads();
  float fn = sqrtf(red[0]+red[1]+red[2]+red[3]);
  int p = tid>>3, e = tid&7;
  float d = 0.f, q = 0.f;
  for (int k=e*32; k<e*32+32; k++){ float pv = protos[p*256+k]; d += ff[k]*pv; q += pv*pv; }
  d += __shfl_xor(d,1); q += __shfl_xor(q,1);
  d += __shfl_xor(d,2); q += __shfl_xor(q,2);
  d += __shfl_xor(d,4); q += __shfl_xor(q,4);
  if (e==0){ simr[p] = d; pnl[p] = sqrtf(q); }
  __syncthreads();
  if (tid < 64){
    float z = (tid<32) ? (2.f*simr[tid]/fmaxf(fn*pnl[tid], 1e-8f)) : -3e38f;
    float m = z;
    #pragma unroll
    for (int off=16; off; off>>=1) m = fmaxf(m, __shfl_xor(m, off));
    float ev = (tid<32) ? expf(z - m) : 0.f;
    float sm = ev;
    #pragma unroll
    for (int off=16; off; off>>=1) sm += __shfl_xor(sm, off);
    if (tid<32) sw[tid] = ev/sm;
  }
  __syncthreads();
  float cs = 0.f;
  #pragma unroll 8
  for (int pp=0;pp<32;pp++) cs += sw[pp]*protos[pp*256+tid];
  cs_out[(long)row*256+tid] = cs;
  csb[tid] = cs;
  __syncthreads();
  if (tid<128){
    float hv = b1[tid];
    for (int k=0;k<256;k++) hv += csb[k]*w1[k*128+tid];
    hid[tid] = fmaxf(hv, 0.f);
  }
  __syncthreads();
  if (tid<16){
    float lv = b2[tid];
    for (int j=0;j<128;j++) lv += hid[j]*w2[j*16+tid];
    logits[(long)row*16+tid] = lv;
  }
}

// ---------- marker_scores broadcast fill ----------
__global__ __launch_bounds__(256) void k_fill_marker(const float* __restrict__ mw,
    float* __restrict__ out){
  int b = blockIdx.y;
  int t = blockIdx.x*256 + threadIdx.x;
  float* base = out + O_MS + (long)b*160000;
  if (t < 40000){
    int i = 4*t;
    float4 A  = *(const float4*)(mw + i);
    float4 Bv = (i+4 < 160000) ? *(const float4*)(mw + i + 4) : *(const float4*)(mw);
    float4 v = make_float4(A.w, Bv.x, Bv.y, Bv.z);
    *(float4*)(base + 3 + i) = v;
  }
  if (b==0 && t<3) base[t] = mw[t];
}

// ---------- marker_importance: per-class L1 normalize (+ sparsity scalar) ----------
__global__ __launch_bounds__(256) void k_importance(const float* __restrict__ mw,
    float* __restrict__ out){
  __shared__ float red[4];
  int c = blockIdx.x, tid = threadIdx.x;
  if (c==0 && tid==0) out[O_SP] = 0.01f/10000.0f;
  float s = 0.f;
  for (int g0=tid; g0<10000; g0+=256) s += fabsf(mw[c*10000+g0]);
  #pragma unroll
  for (int off=32; off; off>>=1) s += __shfl_xor(s, off);
  if ((tid&63)==0) red[tid>>6] = s;
  __syncthreads();
  float inv = 1.f/fmaxf(red[0]+red[1]+red[2]+red[3], 1e-12f);
  for (int g0=tid; g0<10000; g0+=256)
    out[O_MI + (long)c*10000 + g0] = mw[c*10000+g0]*inv;
}

extern "C" void kernel_launch(void* const* d_in, const int* in_sizes, int n_in,
                              void* d_out, int out_size, void* d_ws, size_t ws_size,
                              hipStream_t stream){
  const float* x        = (const float*)d_in[0];
  const float* enc_w1   = (const float*)d_in[1];
  const float* enc_b1   = (const float*)d_in[2];
  const float* enc_ln_g = (const float*)d_in[3];
  const float* enc_ln_b = (const float*)d_in[4];
  const float* enc_w2   = (const float*)d_in[5];
  const float* enc_b2   = (const float*)d_in[6];
  const float* qkv_w    = (const float*)d_in[9];
  const float* qkv_b    = (const float*)d_in[10];
  const float* out_w    = (const float*)d_in[11];
  const float* out_b    = (const float*)d_in[12];
  const float* ln_g     = (const float*)d_in[13];
  const float* ln_b     = (const float*)d_in[14];
  const float* protos   = (const float*)d_in[15];
  const float* clf_w1   = (const float*)d_in[16];
  const float* clf_b1   = (const float*)d_in[17];
  const float* clf_w2   = (const float*)d_in[18];
  const float* clf_b2   = (const float*)d_in[19];
  const float* mw       = (const float*)d_in[20];
  float* out = (float*)d_out;

  char* scr = (char*)(((uintptr_t)d_out + O_MS*4 + 255) & ~(uintptr_t)255);
  unsigned short* xh  = (unsigned short*)(scr);
  unsigned short* wth = (unsigned short*)(scr + 83886080L);
  unsigned short* wtl = (unsigned short*)(scr + 94371840L);
  float* pc = (float*)(scr + 104857600L);   // 8 x 2048 x 512 split-K partials
  float* t1 = (float*)(scr + 138412032L);   // 2048 x 512
  float* f0 = (float*)(scr + 142606336L);   // 2048 x 256
  float* f1 = (float*)(scr + 144703488L);
  float* Wc = (float*)(scr + 146800640L);   // 3 x 256 x 256
  float* bc = (float*)(scr + 147587072L);   // 3 x 256

  k_prep0    <<<51, 256, 0, stream>>>(qkv_w, qkv_b, out_w, out_b, Wc, bc);
  k_split_x  <<<20480, 256, 0, stream>>>(x, xh);
  k_split_w1t<<<dim3(160, 8), 256, 0, stream>>>(enc_w1, wth, wtl);
  k_gemm1    <<<dim3(16, 4, 8), 256, 0, stream>>>(xh, wth, wtl, pc);
  k_reduce_ln<<<2048, 256, 0, stream>>>(pc, enc_b1, enc_ln_g, enc_ln_b, t1);
  k_rowgemm  <<<512, 256, 0, stream>>>(t1, enc_w2, enc_b2, enc_ln_g, enc_ln_b, f0, 512, 0);
  const float* fin = f0; float* fo = f1;
  for (int i=0;i<3;i++){
    k_rowgemm<<<512, 256, 0, stream>>>(fin, Wc + (long)i*65536, bc + i*256,
                                       ln_g + i*256, ln_b + i*256, fo, 256, 1);
    const float* tmp = fo; fo = (float*)fin; fin = tmp;
  }
  k_head     <<<2048, 256, 0, stream>>>(fin, protos, clf_w1, clf_b1, clf_w2, clf_b2,
                                        out, out + O_CS);
  k_fill_marker<<<dim3(157, 2048), 256, 0, stream>>>(mw, out);   // overwrites scratch
  k_importance <<<16, 256, 0, stream>>>(mw, out);
}

// Round 10
// 526.620 us; speedup vs baseline: 2.1062x; 1.1277x over previous
//
#include <hip/hip_runtime.h>
#include <stdint.h>

// ---- problem constants ----
#define GG 10000      // genes
#define H2 512        // 2H
#define KP 10240      // padded K for GEMM1 (32*320, split 8 ways evenly)
#define KCH 1280      // KP/8
#define KSTEPS 40     // KCH/32

// output layout (floats): logits[2048*16] | cell_states[2048*256] | sparsity[1]
//                         | marker_scores[2048*16*10000] | marker_importance[16*10000]
#define O_CS 32768L
#define O_SP 557056L
#define O_MS 557057L
#define O_MI 328237057L

typedef __attribute__((ext_vector_type(8))) short v8s;
typedef __attribute__((ext_vector_type(4))) float v4f;
typedef __attribute__((ext_vector_type(4))) unsigned short u16x4;
typedef __attribute__((ext_vector_type(8))) unsigned short u16x8;

__device__ __forceinline__ unsigned short bf16_rne(float f){
  unsigned u = __float_as_uint(f);
  u += 0x7fffu + ((u>>16)&1u);
  return (unsigned short)(u>>16);
}
__device__ __forceinline__ float bf16_f(unsigned short h){
  return __uint_as_float(((unsigned)h)<<16);
}

// async global->LDS, 16B per lane; lds dest must be wave-uniform base (lane*16 auto)
#define GL16(g,l) __builtin_amdgcn_global_load_lds( \
    (__attribute__((address_space(1))) void*)(uintptr_t)(g), \
    (__attribute__((address_space(3))) void*)(l), 16, 0, 0)

// ---------- prep0: Wc[i] = qkv_w[i][:,512:768] @ out_w[i]; bc[i] = qkv_b_v @ out_w + out_b ----
// (verbatim from R9; numerically proven, absmax 0.00390625)
__global__ __launch_bounds__(256) void k_prep0(const float* __restrict__ qkv_w,
    const float* __restrict__ qkv_b, const float* __restrict__ out_w,
    const float* __restrict__ out_b, float* __restrict__ Wc, float* __restrict__ bc){
  __shared__ float As[64][36];
  __shared__ float WsT[64][36];
  const int bid = blockIdx.x, tid = threadIdx.x;
  if (bid < 48){
    const int z = bid>>4, bx = (bid&15)>>2, by = bid&3;
    const float* A = qkv_w + (long)z*196608 + 512;   // lda=768, V-slice
    const float* W = out_w + (long)z*65536;          // ldw=256
    float* C = Wc + (long)z*65536;
    const int tx = tid&15, ty = tid>>4;
    const int ar = tid>>2, ak = (tid&3)*8;
    const int wr2 = tid>>3, wc2 = (tid&7)*8;
    float acc[4][4];
    #pragma unroll
    for (int i=0;i<4;i++)
      #pragma unroll
      for (int j=0;j<4;j++) acc[i][j] = 0.f;
    for (int kb=0; kb<256; kb+=32){
      float4 a0 = *(const float4*)(A + (long)(bx*64+ar)*768 + kb + ak);
      float4 a1 = *(const float4*)(A + (long)(bx*64+ar)*768 + kb + ak + 4);
      float4 w0 = *(const float4*)(W + (long)(kb+wr2)*256 + by*64 + wc2);
      float4 w1v= *(const float4*)(W + (long)(kb+wr2)*256 + by*64 + wc2 + 4);
      __syncthreads();
      *(float4*)&As[ar][ak]   = a0;
      *(float4*)&As[ar][ak+4] = a1;
      float cw[8] = {w0.x,w0.y,w0.z,w0.w,w1v.x,w1v.y,w1v.z,w1v.w};
      #pragma unroll
      for (int jj=0;jj<8;jj++) WsT[wc2+jj][wr2] = cw[jj];
      __syncthreads();
      #pragma unroll
      for (int k4=0;k4<8;k4++){
        float4 av[4], wv[4];
        #pragma unroll
        for (int i=0;i<4;i++) av[i] = *(const float4*)&As[ty + i*16][k4*4];
        #pragma unroll
        for (int j=0;j<4;j++) wv[j] = *(const float4*)&WsT[tx + j*16][k4*4];
        #pragma unroll
        for (int i=0;i<4;i++)
          #pragma unroll
          for (int j=0;j<4;j++)
            acc[i][j] += av[i].x*wv[j].x + av[i].y*wv[j].y + av[i].z*wv[j].z + av[i].w*wv[j].w;
      }
    }
    #pragma unroll
    for (int i=0;i<4;i++){
      int r = bx*64 + ty + i*16;
      #pragma unroll
      for (int j=0;j<4;j++)
        C[(long)r*256 + by*64 + tx + j*16] = acc[i][j];
    }
  } else {
    int i = bid - 48;                      // 0..2
    float acc = out_b[i*256 + tid];
    const float* wo = out_w + (long)i*65536;
    const float* qb = qkv_b + i*768 + 512;
    for (int j=0;j<256;j++) acc += qb[j]*wo[j*256+tid];
    bc[i*256+tid] = acc;
  }
}

// ---------- split x (2048 x 10000 fp32) -> x_hi bf16 (2048 x 10240, zero pad) ----------
__global__ __launch_bounds__(256) void k_split_x(const float* __restrict__ x,
    unsigned short* __restrict__ xh){
  int idx = blockIdx.x*256 + threadIdx.x;           // 2048*2560 chunks of 4
  int row = idx / (KP/4);
  int k = (idx - row*(KP/4))*4;
  float4 v = make_float4(0.f,0.f,0.f,0.f);
  if (k < GG) v = *(const float4*)(x + (long)row*GG + k);
  float c[4] = {v.x,v.y,v.z,v.w};
  u16x4 hv;
  #pragma unroll
  for (int j=0;j<4;j++) hv[j] = bf16_rne(c[j]);
  *(u16x4*)(xh + (long)row*KP + k) = hv;
}

// ---------- split+transpose enc_w1 (10000 x 512) -> w1t_hi/lo (512 x 10240 bf16) ----------
__global__ __launch_bounds__(256) void k_split_w1t(const float* __restrict__ w1,
    unsigned short* __restrict__ wth, unsigned short* __restrict__ wtl){
  __shared__ unsigned T[64][65];
  int k0 = blockIdx.x*64, n0 = blockIdx.y*64;
  int tid = threadIdx.x;
  {
    int kr = tid>>2, nc = (tid&3)*16;
    int kk = k0 + kr;
    #pragma unroll
    for (int j=0;j<16;j+=4){
      float4 v = make_float4(0.f,0.f,0.f,0.f);
      if (kk < GG) v = *(const float4*)(w1 + (long)kk*H2 + n0 + nc + j);
      float c[4] = {v.x,v.y,v.z,v.w};
      #pragma unroll
      for (int jj=0;jj<4;jj++){
        unsigned short h = bf16_rne(c[jj]);
        unsigned short l = bf16_rne(c[jj] - bf16_f(h));
        T[kr][nc+j+jj] = (unsigned)h | ((unsigned)l<<16);
      }
    }
  }
  __syncthreads();
  {
    int n = tid>>2, kc = (tid&3)*16;
    u16x8 h0, h1, l0, l1;
    #pragma unroll
    for (int j=0;j<8;j++){
      unsigned a = T[kc+j][n];
      unsigned b = T[kc+8+j][n];
      h0[j] = (unsigned short)(a & 0xffffu); l0[j] = (unsigned short)(a>>16);
      h1[j] = (unsigned short)(b & 0xffffu); l1[j] = (unsigned short)(b>>16);
    }
    long off = (long)(n0+n)*KP + k0 + kc;
    *(u16x8*)(wth+off)   = h0; *(u16x8*)(wth+off+8) = h1;
    *(u16x8*)(wtl+off)   = l0; *(u16x8*)(wtl+off+8) = l1;
  }
}

// ---------- GEMM1: (2048x10240) @ (10240x512) 2-term split-bf16 MFMA, split-K=8 ----------
// h = x_hi*(w_hi + w_lo)  (R5 measured-best version, unchanged)
__global__ __launch_bounds__(256) void k_gemm1(
    const unsigned short* __restrict__ xh,
    const unsigned short* __restrict__ wth, const unsigned short* __restrict__ wtl,
    float* __restrict__ pc){
  __shared__ unsigned short Ah[4096], Bh[4096], Bl[4096]; // [128 rows][32 k] bf16 each
  const int tid = threadIdx.x;
  const int wid = tid>>6, lane = tid&63;
  const int bm = blockIdx.x, bn = blockIdx.y, kz = blockIdx.z;
  const int c0 = wid*2, c1 = c0+1;
  const int srow = lane>>2;
  const int sk8 = (lane&3)*8;
  const long kb0 = (long)kz*KCH + sk8;
  const long rA0 = (long)(bm*128 + c0*16 + srow)*KP + kb0;
  const long rA1 = (long)(bm*128 + c1*16 + srow)*KP + kb0;
  const long rB0 = (long)(bn*128 + c0*16 + srow)*KP + kb0;
  const long rB1 = (long)(bn*128 + c1*16 + srow)*KP + kb0;
  const unsigned short* pAh0 = xh + rA0;  const unsigned short* pAh1 = xh + rA1;
  const unsigned short* pBh0 = wth + rB0; const unsigned short* pBh1 = wth + rB1;
  const unsigned short* pBl0 = wtl + rB0; const unsigned short* pBl1 = wtl + rB1;
  unsigned short* dAh0 = &Ah[c0*512]; unsigned short* dAh1 = &Ah[c1*512];
  unsigned short* dBh0 = &Bh[c0*512]; unsigned short* dBh1 = &Bh[c1*512];
  unsigned short* dBl0 = &Bl[c0*512]; unsigned short* dBl1 = &Bl[c1*512];
  const int wr = wid>>1, wc = wid&1;      // wave -> 64x64 quadrant
  const int fr = lane&15, fq = lane>>4;
  v4f acc[4][4];
  #pragma unroll
  for (int m=0;m<4;m++)
    #pragma unroll
    for (int n=0;n<4;n++){ v4f z = {0.f,0.f,0.f,0.f}; acc[m][n] = z; }

  for (int s=0; s<KSTEPS; ++s){
    GL16(pAh0, dAh0); GL16(pAh1, dAh1);
    GL16(pBh0, dBh0); GL16(pBh1, dBh1);
    GL16(pBl0, dBl0); GL16(pBl1, dBl1);
    pAh0 += 32; pAh1 += 32;
    pBh0 += 32; pBh1 += 32; pBl0 += 32; pBl1 += 32;
    __syncthreads();                        // drains vmcnt -> LDS tiles ready
    v8s ah[4], bh[4], bl[4];
    #pragma unroll
    for (int m=0;m<4;m++)
      ah[m] = *(const v8s*)&Ah[(wr*64 + m*16 + fr)*32 + fq*8];
    #pragma unroll
    for (int n=0;n<4;n++){
      int off = (wc*64 + n*16 + fr)*32 + fq*8;
      bh[n] = *(const v8s*)&Bh[off];
      bl[n] = *(const v8s*)&Bl[off];
    }
    #pragma unroll
    for (int m=0;m<4;m++)
      #pragma unroll
      for (int n=0;n<4;n++){
        acc[m][n] = __builtin_amdgcn_mfma_f32_16x16x32_bf16(ah[m], bh[n], acc[m][n], 0,0,0);
        acc[m][n] = __builtin_amdgcn_mfma_f32_16x16x32_bf16(ah[m], bl[n], acc[m][n], 0,0,0);
      }
    __syncthreads();                        // protect LDS from next stage
  }
  float* op = pc + (long)kz*(2048L*512L);
  #pragma unroll
  for (int m=0;m<4;m++){
    #pragma unroll
    for (int n=0;n<4;n++){
      int col = bn*128 + wc*64 + n*16 + fr;
      #pragma unroll
      for (int r=0;r<4;r++){
        int row = bm*128 + wr*64 + m*16 + fq*4 + r;   // C/D: col=lane&15, row=(lane>>4)*4+r
        op[(long)row*512 + col] = acc[m][n][r];
      }
    }
  }
}

// ---------- reduce split-K partials + bias + LayerNorm + ReLU -> t1 (2048x512) ----------
__global__ __launch_bounds__(256) void k_reduce_ln(const float* __restrict__ pc,
    const float* __restrict__ b1, const float* __restrict__ g, const float* __restrict__ b,
    float* __restrict__ t1){
  __shared__ float red[8];
  int row = blockIdx.x, tid = threadIdx.x;
  long base = (long)row*512;
  float v0 = b1[tid], v1 = b1[tid+256];
  #pragma unroll
  for (int kz=0;kz<8;kz++){
    v0 += pc[(long)kz*1048576 + base + tid];
    v1 += pc[(long)kz*1048576 + base + tid + 256];
  }
  float s = v0+v1, q = v0*v0 + v1*v1;
  #pragma unroll
  for (int off=32; off; off>>=1){ s += __shfl_xor(s, off); q += __shfl_xor(q, off); }
  if ((tid&63)==0){ red[tid>>6] = s; red[4+(tid>>6)] = q; }
  __syncthreads();
  float sum = red[0]+red[1]+red[2]+red[3];
  float ssq = red[4]+red[5]+red[6]+red[7];
  float mean = sum*(1.f/512.f);
  float var  = ssq*(1.f/512.f) - mean*mean;
  float rstd = rsqrtf(var + 1e-5f);
  float r0 = (v0-mean)*rstd*g[tid]     + b[tid];
  float r1 = (v1-mean)*rstd*g[tid+256] + b[tid+256];
  t1[base+tid]     = fmaxf(r0, 0.f);
  t1[base+tid+256] = fmaxf(r1, 0.f);
}

// ---------- generic small fp32 GEMM: C(2048xN=256ish) = A @ W + bias, 64x64 tile ----------
__global__ __launch_bounds__(256) void k_gemm_f32(
    const float* __restrict__ A, int lda,
    const float* __restrict__ W, int ldw,
    const float* __restrict__ bias,
    float* __restrict__ C, int ldo, int K){
  __shared__ float As[64][36];
  __shared__ float WsT[64][36];   // [col][k]
  const int tid = threadIdx.x;
  const int bx = blockIdx.x, by = blockIdx.y;
  const int tx = tid&15, ty = tid>>4;
  const int ar = tid>>2, ak = (tid&3)*8;
  const int wr2 = tid>>3, wc2 = (tid&7)*8;
  float acc[4][4];
  #pragma unroll
  for (int i=0;i<4;i++)
    #pragma unroll
    for (int j=0;j<4;j++) acc[i][j] = 0.f;
  for (int kb=0; kb<K; kb+=32){
    float4 a0 = *(const float4*)(A + (long)(bx*64+ar)*lda + kb + ak);
    float4 a1 = *(const float4*)(A + (long)(bx*64+ar)*lda + kb + ak + 4);
    float4 w0 = *(const float4*)(W + (long)(kb+wr2)*ldw + by*64 + wc2);
    float4 w1v= *(const float4*)(W + (long)(kb+wr2)*ldw + by*64 + wc2 + 4);
    __syncthreads();
    *(float4*)&As[ar][ak]   = a0;
    *(float4*)&As[ar][ak+4] = a1;
    float cw[8] = {w0.x,w0.y,w0.z,w0.w,w1v.x,w1v.y,w1v.z,w1v.w};
    #pragma unroll
    for (int jj=0;jj<8;jj++) WsT[wc2+jj][wr2] = cw[jj];
    __syncthreads();
    #pragma unroll
    for (int k4=0;k4<8;k4++){
      float4 av[4], wv[4];
      #pragma unroll
      for (int i=0;i<4;i++) av[i] = *(const float4*)&As[ty + i*16][k4*4];
      #pragma unroll
      for (int j=0;j<4;j++) wv[j] = *(const float4*)&WsT[tx + j*16][k4*4];
      #pragma unroll
      for (int i=0;i<4;i++)
        #pragma unroll
        for (int j=0;j<4;j++)
          acc[i][j] += av[i].x*wv[j].x + av[i].y*wv[j].y + av[i].z*wv[j].z + av[i].w*wv[j].w;
    }
  }
  #pragma unroll
  for (int i=0;i<4;i++){
    int r = bx*64 + ty + i*16;
    #pragma unroll
    for (int j=0;j<4;j++){
      int c = by*64 + tx + j*16;
      C[(long)r*ldo + c] = acc[i][j] + bias[c];
    }
  }
}

// ---------- residual add + LayerNorm over 256 ----------
__global__ __launch_bounds__(256) void k_add_ln(const float* __restrict__ o,
    const float* __restrict__ res, const float* __restrict__ g, const float* __restrict__ b,
    float* __restrict__ fout){
  __shared__ float red[8];
  int row = blockIdx.x, tid = threadIdx.x;
  long base = (long)row*256;
  float x = o[base+tid] + res[base+tid];
  float s = x, q = x*x;
  #pragma unroll
  for (int off=32; off; off>>=1){ s += __shfl_xor(s, off); q += __shfl_xor(q, off); }
  if ((tid&63)==0){ red[tid>>6] = s; red[4+(tid>>6)] = q; }
  __syncthreads();
  float sum = red[0]+red[1]+red[2]+red[3];
  float ssq = red[4]+red[5]+red[6]+red[7];
  float mean = sum*(1.f/256.f);
  float var  = ssq*(1.f/256.f) - mean*mean;
  float rstd = rsqrtf(var + 1e-5f);
  fout[base+tid] = (x-mean)*rstd*g[tid] + b[tid];
}

// ---------- head: cosine sim -> softmax/0.5 -> cell_states -> MLP logits ----------
__global__ __launch_bounds__(256) void k_head(const float* __restrict__ f,
    const float* __restrict__ protos, const float* __restrict__ w1, const float* __restrict__ b1,
    const float* __restrict__ w2, const float* __restrict__ b2,
    float* __restrict__ logits, float* __restrict__ cs_out){
  __shared__ float ff[256], csb[256], hid[128], simr[32], pnl[32], sw[32], red[8];
  int row = blockIdx.x, tid = threadIdx.x;
  float fv = f[(long)row*256 + tid];
  ff[tid] = fv;
  float s = fv*fv;
  #pragma unroll
  for (int off=32; off; off>>=1) s += __shfl_xor(s, off);
  if ((tid&63)==0) red[tid>>6] = s;
  __syncthreads();
  float fn = sqrtf(red[0]+red[1]+red[2]+red[3]);
  int p = tid>>3, e = tid&7;
  float d = 0.f, q = 0.f;
  for (int k=e*32; k<e*32+32; k++){ float pv = protos[p*256+k]; d += ff[k]*pv; q += pv*pv; }
  d += __shfl_xor(d,1); q += __shfl_xor(q,1);
  d += __shfl_xor(d,2); q += __shfl_xor(q,2);
  d += __shfl_xor(d,4); q += __shfl_xor(q,4);
  if (e==0){ simr[p] = d; pnl[p] = sqrtf(q); }
  __syncthreads();
  if (tid < 64){
    float z = (tid<32) ? (2.f*simr[tid]/fmaxf(fn*pnl[tid], 1e-8f)) : -3e38f;
    float m = z;
    #pragma unroll
    for (int off=16; off; off>>=1) m = fmaxf(m, __shfl_xor(m, off));
    float ev = (tid<32) ? expf(z - m) : 0.f;
    float sm = ev;
    #pragma unroll
    for (int off=16; off; off>>=1) sm += __shfl_xor(sm, off);
    if (tid<32) sw[tid] = ev/sm;
  }
  __syncthreads();
  float cs = 0.f;
  #pragma unroll 8
  for (int pp=0;pp<32;pp++) cs += sw[pp]*protos[pp*256+tid];
  cs_out[(long)row*256+tid] = cs;
  csb[tid] = cs;
  __syncthreads();
  if (tid<128){
    float hv = b1[tid];
    for (int k=0;k<256;k++) hv += csb[k]*w1[k*128+tid];
    hid[tid] = fmaxf(hv, 0.f);
  }
  __syncthreads();
  if (tid<16){
    float lv = b2[tid];
    for (int j=0;j<128;j++) lv += hid[j]*w2[j*16+tid];
    logits[(long)row*16+tid] = lv;
  }
}

// ---------- marker_scores broadcast fill (1.31 GB, aligned float4 despite odd base) ----------
__global__ __launch_bounds__(256) void k_fill_marker(const float* __restrict__ mw,
    float* __restrict__ out){
  int b = blockIdx.y;
  int t = blockIdx.x*256 + threadIdx.x;
  float* base = out + O_MS + (long)b*160000;
  if (t < 40000){
    int i = 4*t;
    float4 A  = *(const float4*)(mw + i);
    float4 Bv = (i+4 < 160000) ? *(const float4*)(mw + i + 4) : *(const float4*)(mw);
    float4 v = make_float4(A.w, Bv.x, Bv.y, Bv.z);     // region elems 3+4t .. 6+4t
    *(float4*)(base + 3 + i) = v;                      // 16B-aligned: (O_MS+3)%4==0
  }
  if (b==0 && t<3) base[t] = mw[t];                    // head of copy 0
}

// ---------- marker_importance: per-class L1 normalize (+ sparsity scalar) ----------
__global__ __launch_bounds__(256) void k_importance(const float* __restrict__ mw,
    float* __restrict__ out){
  __shared__ float red[4];
  int c = blockIdx.x, tid = threadIdx.x;
  if (c==0 && tid==0) out[O_SP] = 0.01f/10000.0f;      // softmax rows sum to 1
  float s = 0.f;
  for (int g0=tid; g0<10000; g0+=256) s += fabsf(mw[c*10000+g0]);
  #pragma unroll
  for (int off=32; off; off>>=1) s += __shfl_xor(s, off);
  if ((tid&63)==0) red[tid>>6] = s;
  __syncthreads();
  float inv = 1.f/fmaxf(red[0]+red[1]+red[2]+red[3], 1e-12f);
  for (int g0=tid; g0<10000; g0+=256)
    out[O_MI + (long)c*10000 + g0] = mw[c*10000+g0]*inv;
}

extern "C" void kernel_launch(void* const* d_in, const int* in_sizes, int n_in,
                              void* d_out, int out_size, void* d_ws, size_t ws_size,
                              hipStream_t stream){
  const float* x        = (const float*)d_in[0];
  const float* enc_w1   = (const float*)d_in[1];
  const float* enc_b1   = (const float*)d_in[2];
  const float* enc_ln_g = (const float*)d_in[3];
  const float* enc_ln_b = (const float*)d_in[4];
  const float* enc_w2   = (const float*)d_in[5];
  const float* enc_b2   = (const float*)d_in[6];
  // d_in[7] mod_assign, d_in[8] mod_inter: analytically folded / unused
  const float* qkv_w    = (const float*)d_in[9];
  const float* qkv_b    = (const float*)d_in[10];
  const float* out_w    = (const float*)d_in[11];
  const float* out_b    = (const float*)d_in[12];
  const float* ln_g     = (const float*)d_in[13];
  const float* ln_b     = (const float*)d_in[14];
  const float* protos   = (const float*)d_in[15];
  const float* clf_w1   = (const float*)d_in[16];
  const float* clf_b1   = (const float*)d_in[17];
  const float* clf_w2   = (const float*)d_in[18];
  const float* clf_b2   = (const float*)d_in[19];
  const float* mw       = (const float*)d_in[20];
  float* out = (float*)d_out;

  // scratch lives inside the marker_scores region (filled last); ~150 MB of 1.31 GB
  char* scr = (char*)(((uintptr_t)d_out + O_MS*4 + 255) & ~(uintptr_t)255);
  unsigned short* xh  = (unsigned short*)(scr);
  unsigned short* wth = (unsigned short*)(scr + 83886080L);
  unsigned short* wtl = (unsigned short*)(scr + 94371840L);
  float* pc = (float*)(scr + 104857600L);   // 8 x 2048 x 512 split-K partials
  float* t1 = (float*)(scr + 138412032L);   // 2048 x 512
  float* f0 = (float*)(scr + 142606336L);   // 2048 x 256
  float* f1 = (float*)(scr + 144703488L);
  float* ob = (float*)(scr + 146800640L);   // 2048 x 256
  float* Wc = (float*)(scr + 148897792L);   // 3 x 256 x 256
  float* bc = (float*)(scr + 149684224L);   // 3 x 256

  k_prep0    <<<51, 256, 0, stream>>>(qkv_w, qkv_b, out_w, out_b, Wc, bc);
  k_split_x  <<<20480, 256, 0, stream>>>(x, xh);
  k_split_w1t<<<dim3(160, 8), 256, 0, stream>>>(enc_w1, wth, wtl);
  k_gemm1    <<<dim3(16, 4, 8), 256, 0, stream>>>(xh, wth, wtl, pc);
  k_reduce_ln<<<2048, 256, 0, stream>>>(pc, enc_b1, enc_ln_g, enc_ln_b, t1);
  k_gemm_f32 <<<dim3(32, 4), 256, 0, stream>>>(t1, 512, enc_w2, 256, enc_b2, f0, 256, 512);
  const float* fin = f0; float* fo = f1;
  for (int i=0;i<3;i++){
    // layer collapsed: o = f @ Wc[i] + bc[i]  (Wc = Wv@Wo precomputed in prep0)
    k_gemm_f32<<<dim3(32,4), 256, 0, stream>>>(fin, 256, Wc + (long)i*65536, 256,
                                               bc + i*256, ob, 256, 256);
    k_add_ln  <<<2048, 256, 0, stream>>>(ob, fin, ln_g + i*256, ln_b + i*256, fo);
    const float* tmp = fo; fo = (float*)fin; fin = tmp;
  }
  k_head<<<2048, 256, 0, stream>>>(fin, protos, clf_w1, clf_b1, clf_w2, clf_b2,
                                   out, out + O_CS);
  k_fill_marker<<<dim3(157, 2048), 256, 0, stream>>>(mw, out);   // overwrites scratch
  k_importance <<<16, 256, 0, stream>>>(mw, out);                // after fill (tail overlap)
}